// Round 5
// baseline (258.138 us; speedup 1.0000x reference)
//
#include <hip/hip_runtime.h>
#include <math.h>

#define B 8
#define S 1024
#define D 1024
#define F 3584

#define KSV 64     // split-K chunks for 1024x1024 matvecs (16 rows each)
#define CHV 16
#define KS5 16     // gate/up split-K chunks (64 rows each)
#define CH5 64
#define KS6 112    // down split-K chunks (32 rows each)
#define CH6 32

#define LD4(p) (*(const float4*)(p))
#define FMA4(A, s, W) { (A).x += (s)*(W).x; (A).y += (s)*(W).y; (A).z += (s)*(W).z; (A).w += (s)*(W).w; }

// 8-row FMA step for one token-batch bb against weight regs w0..w7
#define BB8(bb, ACC, XS, CH, koff) { \
  float4 xa = LD4((XS) + (bb)*(CH) + (koff)); \
  float4 xb = LD4((XS) + (bb)*(CH) + (koff) + 4); \
  FMA4(ACC, xa.x, w0); FMA4(ACC, xa.y, w1); FMA4(ACC, xa.z, w2); FMA4(ACC, xa.w, w3); \
  FMA4(ACC, xb.x, w4); FMA4(ACC, xb.y, w5); FMA4(ACC, xb.z, w6); FMA4(ACC, xb.w, w7); }

#define ALL8(XS, CH, koff) \
  BB8(0, acc0, XS, CH, koff) BB8(1, acc1, XS, CH, koff) \
  BB8(2, acc2, XS, CH, koff) BB8(3, acc3, XS, CH, koff) \
  BB8(4, acc4, XS, CH, koff) BB8(5, acc5, XS, CH, koff) \
  BB8(6, acc6, XS, CH, koff) BB8(7, acc7, XS, CH, koff)

// ---------------- block-wide sum for 256-thread blocks ----------------
__device__ __forceinline__ float block_sum256(float v, volatile float* buf) {
  #pragma unroll
  for (int o = 32; o; o >>= 1) v += __shfl_down(v, o);   // wave64 reduce
  __syncthreads();
  if ((threadIdx.x & 63) == 0) buf[threadIdx.x >> 6] = v;
  __syncthreads();
  return buf[0] + buf[1] + buf[2] + buf[3];
}

// 16-row x 1024-col x 8-token matvec step. Wp offset to (chunk row 0, col j).
__device__ __forceinline__ void mv16(const float4* __restrict__ Wp,
                                     float* __restrict__ Pout,
                                     const float* xs, int j) {
  const int st = D / 4;
  float4 acc0 = {0,0,0,0}, acc1 = {0,0,0,0}, acc2 = {0,0,0,0}, acc3 = {0,0,0,0};
  float4 acc4 = {0,0,0,0}, acc5 = {0,0,0,0}, acc6 = {0,0,0,0}, acc7 = {0,0,0,0};
  float4 w0 = Wp[0*st], w1 = Wp[1*st], w2 = Wp[2*st], w3 = Wp[3*st];
  float4 w4 = Wp[4*st], w5 = Wp[5*st], w6 = Wp[6*st], w7 = Wp[7*st];
  float4 v0 = Wp[8*st], v1 = Wp[9*st], v2 = Wp[10*st], v3 = Wp[11*st];
  float4 v4 = Wp[12*st], v5 = Wp[13*st], v6 = Wp[14*st], v7 = Wp[15*st];
  ALL8(xs, CHV, 0);
  w0 = v0; w1 = v1; w2 = v2; w3 = v3; w4 = v4; w5 = v5; w6 = v6; w7 = v7;
  ALL8(xs, CHV, 8);
  *(float4*)(Pout + 0*(size_t)D + j) = acc0;
  *(float4*)(Pout + 1*(size_t)D + j) = acc1;
  *(float4*)(Pout + 2*(size_t)D + j) = acc2;
  *(float4*)(Pout + 3*(size_t)D + j) = acc3;
  *(float4*)(Pout + 4*(size_t)D + j) = acc4;
  *(float4*)(Pout + 5*(size_t)D + j) = acc5;
  *(float4*)(Pout + 6*(size_t)D + j) = acc6;
  *(float4*)(Pout + 7*(size_t)D + j) = acc7;
}

// K1: rmsnorm-1 folded into V-matvec. Each of 64 blocks redundantly computes
// the 8 per-token rms scales (wave-parallel: each wave handles 2 tokens), then
// stages its 16-row slice of h1 = hs*sc*ln1 into LDS and runs the matvec.
__global__ __launch_bounds__(256, 2) void k_mvp_v(const float* __restrict__ hs,
                                                  const float* __restrict__ ln1w,
                                                  const float* __restrict__ vw,
                                                  float* __restrict__ Vp) {
  __shared__ float xs[8 * CHV];
  __shared__ float scsh[8];
  int tid = threadIdx.x;
  int w = tid >> 6, lane = tid & 63;
  #pragma unroll
  for (int b2 = 0; b2 < 2; b2++) {
    int b = w * 2 + b2;
    const float4* hp = (const float4*)(hs + (size_t)b * S * D);
    float ss = 0.f;
    #pragma unroll
    for (int t = 0; t < 4; t++) {
      float4 v = hp[lane * 4 + t];           // 64 B contiguous per lane
      ss += v.x*v.x + v.y*v.y + v.z*v.z + v.w*v.w;
    }
    #pragma unroll
    for (int o = 32; o; o >>= 1) ss += __shfl_down(ss, o);
    if (lane == 0) scsh[b] = rsqrtf(ss * (1.f / (float)D) + 1e-6f);
  }
  __syncthreads();
  int i0 = blockIdx.x * CHV;
  if (tid < 128) {
    int bb = tid >> 4, ii = tid & 15;
    xs[tid] = hs[(size_t)bb * S * D + i0 + ii] * scsh[bb] * ln1w[i0 + ii];
  }
  __syncthreads();
  int j = tid * 4;
  mv16((const float4*)(vw + (size_t)i0 * D + j), Vp + (size_t)blockIdx.x * 8 * D, xs, j);
}

// K2: reduce Vp slice -> LDS, then O-projection partials.
__global__ __launch_bounds__(256, 2) void k_ored(const float* __restrict__ Vp,
                                                 const float* __restrict__ ow,
                                                 float* __restrict__ Op) {
  __shared__ float xs[8 * CHV];
  int tid = threadIdx.x;
  int i0 = blockIdx.x * CHV;
  if (tid < 128) {
    int bb = tid >> 4, ii = tid & 15;
    float s = 0.f;
    #pragma unroll 16
    for (int p = 0; p < KSV; p++) s += Vp[((size_t)p * 8 + bb) * D + i0 + ii];
    xs[bb * CHV + ii] = s;
  }
  __syncthreads();
  int j = tid * 4;
  mv16((const float4*)(ow + (size_t)i0 * D + j), Op + (size_t)blockIdx.x * 8 * D, xs, j);
}

// K3: xr = hs + attn_out; h2 = rmsnorm(xr, ln2); router top-1. grid=8.
__global__ void k_mid(const float* __restrict__ hs, const float* __restrict__ Op,
                      const float* __restrict__ ln2, const float* __restrict__ rw,
                      float* __restrict__ xr, float* __restrict__ h2,
                      float* __restrict__ topw, int* __restrict__ sel) {
  __shared__ float buf[4];
  int b = blockIdx.x;
  int idx = threadIdx.x * 4;
  float4 x = LD4(hs + (size_t)b * S * D + idx);
  #pragma unroll 16
  for (int p = 0; p < KSV; p++) {
    float4 v = LD4(Op + ((size_t)p * 8 + b) * D + idx);
    x.x += v.x; x.y += v.y; x.z += v.z; x.w += v.w;
  }
  *(float4*)(xr + b * D + idx) = x;
  float ss = x.x*x.x + x.y*x.y + x.z*x.z + x.w*x.w;
  float tot = block_sum256(ss, buf);
  float sc = rsqrtf(tot * (1.f / (float)D) + 1e-6f);
  float4 wv = LD4(ln2 + idx);
  float4 h;
  h.x = x.x*sc*wv.x; h.y = x.y*sc*wv.y; h.z = x.z*sc*wv.z; h.w = x.w*sc*wv.w;
  *(float4*)(h2 + b * D + idx) = h;
  float r0 = h.x * rw[idx * 2]     + h.y * rw[(idx + 1) * 2] +
             h.z * rw[(idx + 2) * 2] + h.w * rw[(idx + 3) * 2];
  float r1 = h.x * rw[idx * 2 + 1]     + h.y * rw[(idx + 1) * 2 + 1] +
             h.z * rw[(idx + 2) * 2 + 1] + h.w * rw[(idx + 3) * 2 + 1];
  r0 = block_sum256(r0, buf);
  r1 = block_sum256(r1, buf);
  if (threadIdx.x == 0) {
    float m = fmaxf(r0, r1);
    float e0 = __expf(r0 - m), e1 = __expf(r1 - m);
    float inv = 1.f / (e0 + e1);
    float p0 = e0 * inv, p1 = e1 * inv;
    topw[b] = fmaxf(p0, p1);
    sel[b] = (p1 > p0) ? 1 : 0;
  }
}

// K4: gate/up split-K partials over flattened col space of 4 matrices
// (m=0: gate e0, 1: gate e1, 2: up e0, 3: up e1). grid=(14, KS5).
// Stores ONLY tokens routed to the matrix's expert (others are multiplied by 0
// in the reference and never read downstream) -> halves Pgu traffic.
__global__ __launch_bounds__(256, 2) void k_gateup(const float* __restrict__ h2,
                                                   const float* __restrict__ gw,
                                                   const float* __restrict__ uw,
                                                   const int* __restrict__ sel,
                                                   float* __restrict__ Pgu) {
  __shared__ float xs[8 * CH5];
  __shared__ int ssel[8];
  int tid = threadIdx.x;
  int kc = blockIdx.y, colt = blockIdx.x;
  int i0 = kc * CH5;
  { int bb = tid >> 6, r = tid & 63;
    xs[tid]       = h2[bb * D + i0 + r];
    xs[tid + 256] = h2[(bb + 4) * D + i0 + r]; }
  if (tid < 8) ssel[tid] = sel[tid];
  __syncthreads();
  int c = colt * 1024 + tid * 4;     // flattened col over 4 matrices (4*F)
  int m = c / F;
  int j = c - m * F;
  const float* base = (m < 2 ? gw : uw) + (size_t)(m & 1) * D * F;
  const float4* Wp = (const float4*)(base + (size_t)i0 * F + j);
  const int st = F / 4;
  float4 acc0 = {0,0,0,0}, acc1 = {0,0,0,0}, acc2 = {0,0,0,0}, acc3 = {0,0,0,0};
  float4 acc4 = {0,0,0,0}, acc5 = {0,0,0,0}, acc6 = {0,0,0,0}, acc7 = {0,0,0,0};
  float4 w0 = Wp[0*st], w1 = Wp[1*st], w2 = Wp[2*st], w3 = Wp[3*st];
  float4 w4 = Wp[4*st], w5 = Wp[5*st], w6 = Wp[6*st], w7 = Wp[7*st];
  Wp += 8 * st;
  #pragma unroll
  for (int t = 0; t < CH5 / 8 - 1; t++) {
    float4 n0 = Wp[0*st], n1 = Wp[1*st], n2 = Wp[2*st], n3 = Wp[3*st];
    float4 n4 = Wp[4*st], n5 = Wp[5*st], n6 = Wp[6*st], n7 = Wp[7*st];
    Wp += 8 * st;
    ALL8(xs, CH5, t * 8);
    w0 = n0; w1 = n1; w2 = n2; w3 = n3; w4 = n4; w5 = n5; w6 = n6; w7 = n7;
  }
  ALL8(xs, CH5, CH5 - 8);
  int me = m & 1;
  #define GU_ST(bb, ACC) \
    if (ssel[bb] == me) \
      *(float4*)(Pgu + (((size_t)kc * 4 + m) * 8 + (bb)) * F + j) = ACC;
  GU_ST(0, acc0) GU_ST(1, acc1) GU_ST(2, acc2) GU_ST(3, acc3)
  GU_ST(4, acc4) GU_ST(5, acc5) GU_ST(6, acc6) GU_ST(7, acc7)
  #undef GU_ST
}

// K5: silu-reduce Pgu slice -> LDS (selected tokens only), then down partials.
// grid = 2*KS6 (e = bid&1, chunk = bid>>1). Stores predicated on selection.
__global__ __launch_bounds__(256, 2) void k_down(const float* __restrict__ Pgu,
                                                 const float* __restrict__ dw,
                                                 const int* __restrict__ sel,
                                                 float* __restrict__ Dp) {
  __shared__ float xs[8 * CH6];
  __shared__ int ssel[8];
  int tid = threadIdx.x;
  int e = blockIdx.x & 1, ch = blockIdx.x >> 1, i0 = ch * CH6;
  if (tid < 8) ssel[tid] = sel[tid];
  __syncthreads();
  { int bb = tid >> 5, ii = tid & 31;
    float r = 0.f;
    if (ssel[bb] == e) {
      float ga = 0.f, ua = 0.f;
      #pragma unroll
      for (int kc = 0; kc < KS5; kc++) {
        ga += Pgu[(((size_t)kc * 4 + e)     * 8 + bb) * F + i0 + ii];
        ua += Pgu[(((size_t)kc * 4 + 2 + e) * 8 + bb) * F + i0 + ii];
      }
      r = (ga / (1.f + __expf(-ga))) * ua;
    }
    xs[bb * CH6 + ii] = r; }
  __syncthreads();
  int j = tid * 4;
  const float4* Wp = (const float4*)(dw + (size_t)e * F * D + (size_t)i0 * D + j);
  const int st = D / 4;
  float4 acc0 = {0,0,0,0}, acc1 = {0,0,0,0}, acc2 = {0,0,0,0}, acc3 = {0,0,0,0};
  float4 acc4 = {0,0,0,0}, acc5 = {0,0,0,0}, acc6 = {0,0,0,0}, acc7 = {0,0,0,0};
  float4 w0 = Wp[0*st], w1 = Wp[1*st], w2 = Wp[2*st], w3 = Wp[3*st];
  float4 w4 = Wp[4*st], w5 = Wp[5*st], w6 = Wp[6*st], w7 = Wp[7*st];
  Wp += 8 * st;
  #pragma unroll
  for (int t = 0; t < CH6 / 8 - 1; t++) {
    float4 n0 = Wp[0*st], n1 = Wp[1*st], n2 = Wp[2*st], n3 = Wp[3*st];
    float4 n4 = Wp[4*st], n5 = Wp[5*st], n6 = Wp[6*st], n7 = Wp[7*st];
    Wp += 8 * st;
    ALL8(xs, CH6, t * 8);
    w0 = n0; w1 = n1; w2 = n2; w3 = n3; w4 = n4; w5 = n5; w6 = n6; w7 = n7;
  }
  ALL8(xs, CH6, CH6 - 8);
  #define DN_ST(bb, ACC) \
    if (ssel[bb] == e) \
      *(float4*)(Dp + (((size_t)ch * 2 + e) * 8 + (bb)) * D + j) = ACC;
  DN_ST(0, acc0) DN_ST(1, acc1) DN_ST(2, acc2) DN_ST(3, acc3)
  DN_ST(4, acc4) DN_ST(5, acc5) DN_ST(6, acc6) DN_ST(7, acc7)
  #undef DN_ST
}

// K6: x2 = xr + top_w * sum_p Dp[p][sel]; final rmsnorm; logits. grid=8.
__global__ void k_final(const float* __restrict__ xr, const float* __restrict__ Dp,
                        const float* __restrict__ topw, const int* __restrict__ sel,
                        const float* __restrict__ flw, const float* __restrict__ sw,
                        float* __restrict__ out) {
  __shared__ float buf[4];
  int b = blockIdx.x;
  int e = sel[b];
  float tw = topw[b];
  int idx = threadIdx.x * 4;
  float4 y = {0,0,0,0};
  #pragma unroll 16
  for (int p = 0; p < KS6; p++) {
    float4 v = LD4(Dp + (((size_t)p * 2 + e) * 8 + b) * D + idx);
    y.x += v.x; y.y += v.y; y.z += v.z; y.w += v.w;
  }
  float4 x = LD4(xr + b * D + idx);
  x.x += tw * y.x; x.y += tw * y.y; x.z += tw * y.z; x.w += tw * y.w;
  float ss = x.x*x.x + x.y*x.y + x.z*x.z + x.w*x.w;
  float tot = block_sum256(ss, buf);
  float sc = rsqrtf(tot * (1.f / (float)D) + 1e-6f);
  float4 wv = LD4(flw + idx);
  float n0 = x.x*sc*wv.x, n1 = x.y*sc*wv.y, n2 = x.z*sc*wv.z, n3 = x.w*sc*wv.w;
  float l0 = n0 * sw[idx * 2]     + n1 * sw[(idx + 1) * 2] +
             n2 * sw[(idx + 2) * 2] + n3 * sw[(idx + 3) * 2];
  float l1 = n0 * sw[idx * 2 + 1]     + n1 * sw[(idx + 1) * 2 + 1] +
             n2 * sw[(idx + 2) * 2 + 1] + n3 * sw[(idx + 3) * 2 + 1];
  l0 = block_sum256(l0, buf);
  l1 = block_sum256(l1, buf);
  if (threadIdx.x == 0) { out[b * 2 + 0] = l0; out[b * 2 + 1] = l1; }
}

extern "C" void kernel_launch(void* const* d_in, const int* in_sizes, int n_in,
                              void* d_out, int out_size, void* d_ws, size_t ws_size,
                              hipStream_t stream) {
  const float* hs  = (const float*)d_in[0];
  const float* ln1 = (const float*)d_in[1];
  // d_in[2]=q_w, d_in[3]=k_w: dead — token-0 causal attention only needs V.
  const float* vw  = (const float*)d_in[4];
  const float* ow  = (const float*)d_in[5];
  const float* ln2 = (const float*)d_in[6];
  const float* rw  = (const float*)d_in[7];
  const float* gw  = (const float*)d_in[8];
  const float* uw  = (const float*)d_in[9];
  const float* dw  = (const float*)d_in[10];
  const float* flw = (const float*)d_in[11];
  const float* sw  = (const float*)d_in[12];

  float* ws = (float*)d_ws;
  float* Vp   = ws;                     // KSV*8*D  = 524288
  float* Op   = Vp + 524288;            // 524288
  float* xr   = Op + 524288;            // 8192
  float* h2   = xr + 8192;              // 8192
  float* tw8  = h2 + 8192;              // 8
  int*   sel8 = (int*)(tw8 + 8);        // 8
  float* Pgu  = tw8 + 16;               // KS5*4*8*F = 1835008
  float* Dp   = Pgu + 1835008;          // KS6*2*8*D = 1835008
  // no atomics, no barrier -> no zero-init; every read cell is written first.

  k_mvp_v<<<KSV, 256, 0, stream>>>(hs, ln1, vw, Vp);
  k_ored<<<KSV, 256, 0, stream>>>(Vp, ow, Op);
  k_mid<<<8, 256, 0, stream>>>(hs, Op, ln2, rw, xr, h2, tw8, sel8);
  k_gateup<<<dim3(14, KS5), 256, 0, stream>>>(h2, gw, uw, sel8, Pgu);
  k_down<<<2 * KS6, 256, 0, stream>>>(Pgu, dw, sel8, Dp);
  k_final<<<8, 256, 0, stream>>>(xr, Dp, tw8, sel8, flw, sw, (float*)d_out);
}

// Round 6
// 220.914 us; speedup vs baseline: 1.1685x; 1.1685x over previous
//
#include <hip/hip_runtime.h>
#include <math.h>

#define B 8
#define S 1024
#define D 1024
#define F 3584

#define KSV 64     // split-K chunks for 1024x1024 matvecs (16 rows each)
#define CHV 16
#define KS5 32     // gate/up split-K chunks (32 rows each) -> 448 blocks
#define CH5 32
#define KS6 224    // down split-K chunks (16 rows each)    -> 448 blocks
#define CH6 16

#define LD4(p) (*(const float4*)(p))
// Non-temporal 16B load via ext_vector (float4 is a struct; builtin needs a
// real vector type). Weights are single-use: nt -> no LLC allocation -> we
// stop evicting the poison-fill's dirty lines inside our own dispatches.
typedef float f4v __attribute__((ext_vector_type(4)));
#define NTLD(p) __builtin_nontemporal_load((const f4v*)(p))

#define FMA4(A, s, W) { (A).x += (s)*(W).x; (A).y += (s)*(W).y; (A).z += (s)*(W).z; (A).w += (s)*(W).w; }

// 8-row FMA step for one token-batch bb against weight regs w0..w7
#define BB8(bb, ACC, XS, CH, koff) { \
  float4 xa = LD4((XS) + (bb)*(CH) + (koff)); \
  float4 xb = LD4((XS) + (bb)*(CH) + (koff) + 4); \
  FMA4(ACC, xa.x, w0); FMA4(ACC, xa.y, w1); FMA4(ACC, xa.z, w2); FMA4(ACC, xa.w, w3); \
  FMA4(ACC, xb.x, w4); FMA4(ACC, xb.y, w5); FMA4(ACC, xb.z, w6); FMA4(ACC, xb.w, w7); }

#define ALL8(XS, CH, koff) \
  BB8(0, acc0, XS, CH, koff) BB8(1, acc1, XS, CH, koff) \
  BB8(2, acc2, XS, CH, koff) BB8(3, acc3, XS, CH, koff) \
  BB8(4, acc4, XS, CH, koff) BB8(5, acc5, XS, CH, koff) \
  BB8(6, acc6, XS, CH, koff) BB8(7, acc7, XS, CH, koff)

// ---------------- block-wide sum for 256-thread blocks ----------------
__device__ __forceinline__ float block_sum256(float v, volatile float* buf) {
  #pragma unroll
  for (int o = 32; o; o >>= 1) v += __shfl_down(v, o);   // wave64 reduce
  __syncthreads();
  if ((threadIdx.x & 63) == 0) buf[threadIdx.x >> 6] = v;
  __syncthreads();
  return buf[0] + buf[1] + buf[2] + buf[3];
}

// 16-row x 1024-col x 8-token matvec step, nt weight loads.
// Optional per-token store predicate: ssel[bb]==e (ssel=nullptr -> always).
__device__ __forceinline__ void mv16(const float* __restrict__ W, int j,
                                     float* __restrict__ Pout,
                                     const float* xs,
                                     const int* ssel, int e) {
  const float4* Wp = (const float4*)(W + j);
  const int st = D / 4;
  float4 acc0 = {0,0,0,0}, acc1 = {0,0,0,0}, acc2 = {0,0,0,0}, acc3 = {0,0,0,0};
  float4 acc4 = {0,0,0,0}, acc5 = {0,0,0,0}, acc6 = {0,0,0,0}, acc7 = {0,0,0,0};
  f4v w0 = NTLD(Wp+0*st), w1 = NTLD(Wp+1*st), w2 = NTLD(Wp+2*st), w3 = NTLD(Wp+3*st);
  f4v w4 = NTLD(Wp+4*st), w5 = NTLD(Wp+5*st), w6 = NTLD(Wp+6*st), w7 = NTLD(Wp+7*st);
  f4v v0 = NTLD(Wp+8*st), v1 = NTLD(Wp+9*st), v2 = NTLD(Wp+10*st), v3 = NTLD(Wp+11*st);
  f4v v4 = NTLD(Wp+12*st), v5 = NTLD(Wp+13*st), v6 = NTLD(Wp+14*st), v7 = NTLD(Wp+15*st);
  ALL8(xs, CHV, 0);
  w0 = v0; w1 = v1; w2 = v2; w3 = v3; w4 = v4; w5 = v5; w6 = v6; w7 = v7;
  ALL8(xs, CHV, 8);
  #define MV_ST(bb, ACC) \
    if (!ssel || ssel[bb] == e) *(float4*)(Pout + (bb)*(size_t)D + j) = ACC;
  MV_ST(0, acc0) MV_ST(1, acc1) MV_ST(2, acc2) MV_ST(3, acc3)
  MV_ST(4, acc4) MV_ST(5, acc5) MV_ST(6, acc6) MV_ST(7, acc7)
  #undef MV_ST
}

// K1: rmsnorm-1 folded into V-matvec. Each of 64 blocks redundantly computes
// the 8 per-token rms scales (each wave handles 2 tokens), stages its 16-row
// slice of h1 = hs*sc*ln1 into LDS, runs the matvec.
__global__ __launch_bounds__(256, 2) void k_mvp_v(const float* __restrict__ hs,
                                                  const float* __restrict__ ln1w,
                                                  const float* __restrict__ vw,
                                                  float* __restrict__ Vp) {
  __shared__ float xs[8 * CHV];
  __shared__ float scsh[8];
  int tid = threadIdx.x;
  int w = tid >> 6, lane = tid & 63;
  #pragma unroll
  for (int b2 = 0; b2 < 2; b2++) {
    int b = w * 2 + b2;
    const float4* hp = (const float4*)(hs + (size_t)b * S * D);
    float ss = 0.f;
    #pragma unroll
    for (int t = 0; t < 4; t++) {
      float4 v = hp[lane * 4 + t];
      ss += v.x*v.x + v.y*v.y + v.z*v.z + v.w*v.w;
    }
    #pragma unroll
    for (int o = 32; o; o >>= 1) ss += __shfl_down(ss, o);
    if (lane == 0) scsh[b] = rsqrtf(ss * (1.f / (float)D) + 1e-6f);
  }
  __syncthreads();
  int i0 = blockIdx.x * CHV;
  if (tid < 128) {
    int bb = tid >> 4, ii = tid & 15;
    xs[tid] = hs[(size_t)bb * S * D + i0 + ii] * scsh[bb] * ln1w[i0 + ii];
  }
  __syncthreads();
  mv16(vw + (size_t)i0 * D, tid * 4, Vp + (size_t)blockIdx.x * 8 * D, xs, 0, 0);
}

// K2: reduce Vp slice -> LDS, then O-projection partials.
__global__ __launch_bounds__(256, 2) void k_ored(const float* __restrict__ Vp,
                                                 const float* __restrict__ ow,
                                                 float* __restrict__ Op) {
  __shared__ float xs[8 * CHV];
  int tid = threadIdx.x;
  int i0 = blockIdx.x * CHV;
  if (tid < 128) {
    int bb = tid >> 4, ii = tid & 15;
    float s = 0.f;
    #pragma unroll 16
    for (int p = 0; p < KSV; p++) s += Vp[((size_t)p * 8 + bb) * D + i0 + ii];
    xs[bb * CHV + ii] = s;
  }
  __syncthreads();
  mv16(ow + (size_t)i0 * D, tid * 4, Op + (size_t)blockIdx.x * 8 * D, xs, 0, 0);
}

// K3: xr = hs + attn_out; h2 = rmsnorm(xr, ln2); router top-1. grid=8.
__global__ void k_mid(const float* __restrict__ hs, const float* __restrict__ Op,
                      const float* __restrict__ ln2, const float* __restrict__ rw,
                      float* __restrict__ xr, float* __restrict__ h2,
                      float* __restrict__ topw, int* __restrict__ sel) {
  __shared__ float buf[4];
  int b = blockIdx.x;
  int idx = threadIdx.x * 4;
  float4 x = LD4(hs + (size_t)b * S * D + idx);
  #pragma unroll 16
  for (int p = 0; p < KSV; p++) {
    float4 v = LD4(Op + ((size_t)p * 8 + b) * D + idx);
    x.x += v.x; x.y += v.y; x.z += v.z; x.w += v.w;
  }
  *(float4*)(xr + b * D + idx) = x;
  float ss = x.x*x.x + x.y*x.y + x.z*x.z + x.w*x.w;
  float tot = block_sum256(ss, buf);
  float sc = rsqrtf(tot * (1.f / (float)D) + 1e-6f);
  float4 wv = LD4(ln2 + idx);
  float4 h;
  h.x = x.x*sc*wv.x; h.y = x.y*sc*wv.y; h.z = x.z*sc*wv.z; h.w = x.w*sc*wv.w;
  *(float4*)(h2 + b * D + idx) = h;
  float r0 = h.x * rw[idx * 2]     + h.y * rw[(idx + 1) * 2] +
             h.z * rw[(idx + 2) * 2] + h.w * rw[(idx + 3) * 2];
  float r1 = h.x * rw[idx * 2 + 1]     + h.y * rw[(idx + 1) * 2 + 1] +
             h.z * rw[(idx + 2) * 2 + 1] + h.w * rw[(idx + 3) * 2 + 1];
  r0 = block_sum256(r0, buf);
  r1 = block_sum256(r1, buf);
  if (threadIdx.x == 0) {
    float m = fmaxf(r0, r1);
    float e0 = __expf(r0 - m), e1 = __expf(r1 - m);
    float inv = 1.f / (e0 + e1);
    float p0 = e0 * inv, p1 = e1 * inv;
    topw[b] = fmaxf(p0, p1);
    sel[b] = (p1 > p0) ? 1 : 0;
  }
}

// K4: gate/up split-K partials over flattened col space of 4 matrices
// (m=0: gate e0, 1: gate e1, 2: up e0, 3: up e1). grid=(14, KS5) = 448 blocks
// (2 blocks/CU for TLP). Stores only tokens routed to this matrix's expert.
__global__ __launch_bounds__(256, 2) void k_gateup(const float* __restrict__ h2,
                                                   const float* __restrict__ gw,
                                                   const float* __restrict__ uw,
                                                   const int* __restrict__ sel,
                                                   float* __restrict__ Pgu) {
  __shared__ float xs[8 * CH5];
  __shared__ int ssel[8];
  int tid = threadIdx.x;
  int kc = blockIdx.y, colt = blockIdx.x;
  int i0 = kc * CH5;
  { int bb = tid >> 5, r = tid & 31;
    xs[tid] = h2[bb * D + i0 + r]; }
  if (tid < 8) ssel[tid] = sel[tid];
  __syncthreads();
  int c = colt * 1024 + tid * 4;     // flattened col over 4 matrices (4*F)
  int m = c / F;
  int j = c - m * F;
  const float* base = (m < 2 ? gw : uw) + (size_t)(m & 1) * D * F;
  const float4* Wp = (const float4*)(base + (size_t)i0 * F + j);
  const int st = F / 4;
  float4 acc0 = {0,0,0,0}, acc1 = {0,0,0,0}, acc2 = {0,0,0,0}, acc3 = {0,0,0,0};
  float4 acc4 = {0,0,0,0}, acc5 = {0,0,0,0}, acc6 = {0,0,0,0}, acc7 = {0,0,0,0};
  f4v w0 = NTLD(Wp+0*st), w1 = NTLD(Wp+1*st), w2 = NTLD(Wp+2*st), w3 = NTLD(Wp+3*st);
  f4v w4 = NTLD(Wp+4*st), w5 = NTLD(Wp+5*st), w6 = NTLD(Wp+6*st), w7 = NTLD(Wp+7*st);
  Wp += 8 * st;
  #pragma unroll
  for (int t = 0; t < CH5 / 8 - 1; t++) {
    f4v n0 = NTLD(Wp+0*st), n1 = NTLD(Wp+1*st), n2 = NTLD(Wp+2*st), n3 = NTLD(Wp+3*st);
    f4v n4 = NTLD(Wp+4*st), n5 = NTLD(Wp+5*st), n6 = NTLD(Wp+6*st), n7 = NTLD(Wp+7*st);
    Wp += 8 * st;
    ALL8(xs, CH5, t * 8);
    w0 = n0; w1 = n1; w2 = n2; w3 = n3; w4 = n4; w5 = n5; w6 = n6; w7 = n7;
  }
  ALL8(xs, CH5, CH5 - 8);
  int me = m & 1;
  #define GU_ST(bb, ACC) \
    if (ssel[bb] == me) \
      *(float4*)(Pgu + (((size_t)kc * 4 + m) * 8 + (bb)) * F + j) = ACC;
  GU_ST(0, acc0) GU_ST(1, acc1) GU_ST(2, acc2) GU_ST(3, acc3)
  GU_ST(4, acc4) GU_ST(5, acc5) GU_ST(6, acc6) GU_ST(7, acc7)
  #undef GU_ST
}

// K5: silu-reduce Pgu slice -> LDS (selected tokens only), then down partials.
// grid = 2*KS6 = 448 (e = bid&1, chunk = bid>>1). Stores predicated.
__global__ __launch_bounds__(256, 2) void k_down(const float* __restrict__ Pgu,
                                                 const float* __restrict__ dw,
                                                 const int* __restrict__ sel,
                                                 float* __restrict__ Dp) {
  __shared__ float xs[8 * CH6];
  __shared__ int ssel[8];
  int tid = threadIdx.x;
  int e = blockIdx.x & 1, ch = blockIdx.x >> 1, i0 = ch * CH6;
  if (tid < 8) ssel[tid] = sel[tid];
  __syncthreads();
  if (tid < 128) {
    int bb = tid >> 4, ii = tid & 15;
    float r = 0.f;
    if (ssel[bb] == e) {
      float ga = 0.f, ua = 0.f;
      #pragma unroll
      for (int kc = 0; kc < KS5; kc++) {
        ga += Pgu[(((size_t)kc * 4 + e)     * 8 + bb) * F + i0 + ii];
        ua += Pgu[(((size_t)kc * 4 + 2 + e) * 8 + bb) * F + i0 + ii];
      }
      r = (ga / (1.f + __expf(-ga))) * ua;
    }
    xs[bb * CH6 + ii] = r;
  }
  __syncthreads();
  mv16(dw + (size_t)e * F * D + (size_t)i0 * D, tid * 4,
       Dp + (((size_t)ch * 2 + e) * 8) * D, xs, ssel, e);
}

// K6: x2 = xr + top_w * sum_p Dp[p][sel]; final rmsnorm; logits. grid=8.
__global__ void k_final(const float* __restrict__ xr, const float* __restrict__ Dp,
                        const float* __restrict__ topw, const int* __restrict__ sel,
                        const float* __restrict__ flw, const float* __restrict__ sw,
                        float* __restrict__ out) {
  __shared__ float buf[4];
  int b = blockIdx.x;
  int e = sel[b];
  float tw = topw[b];
  int idx = threadIdx.x * 4;
  float4 y = {0,0,0,0};
  #pragma unroll 16
  for (int p = 0; p < KS6; p++) {
    float4 v = LD4(Dp + (((size_t)p * 2 + e) * 8 + b) * D + idx);
    y.x += v.x; y.y += v.y; y.z += v.z; y.w += v.w;
  }
  float4 x = LD4(xr + b * D + idx);
  x.x += tw * y.x; x.y += tw * y.y; x.z += tw * y.z; x.w += tw * y.w;
  float ss = x.x*x.x + x.y*x.y + x.z*x.z + x.w*x.w;
  float tot = block_sum256(ss, buf);
  float sc = rsqrtf(tot * (1.f / (float)D) + 1e-6f);
  float4 wv = LD4(flw + idx);
  float n0 = x.x*sc*wv.x, n1 = x.y*sc*wv.y, n2 = x.z*sc*wv.z, n3 = x.w*sc*wv.w;
  float l0 = n0 * sw[idx * 2]     + n1 * sw[(idx + 1) * 2] +
             n2 * sw[(idx + 2) * 2] + n3 * sw[(idx + 3) * 2];
  float l1 = n0 * sw[idx * 2 + 1]     + n1 * sw[(idx + 1) * 2 + 1] +
             n2 * sw[(idx + 2) * 2 + 1] + n3 * sw[(idx + 3) * 2 + 1];
  l0 = block_sum256(l0, buf);
  l1 = block_sum256(l1, buf);
  if (threadIdx.x == 0) { out[b * 2 + 0] = l0; out[b * 2 + 1] = l1; }
}

extern "C" void kernel_launch(void* const* d_in, const int* in_sizes, int n_in,
                              void* d_out, int out_size, void* d_ws, size_t ws_size,
                              hipStream_t stream) {
  const float* hs  = (const float*)d_in[0];
  const float* ln1 = (const float*)d_in[1];
  // d_in[2]=q_w, d_in[3]=k_w: dead — token-0 causal attention only needs V.
  const float* vw  = (const float*)d_in[4];
  const float* ow  = (const float*)d_in[5];
  const float* ln2 = (const float*)d_in[6];
  const float* rw  = (const float*)d_in[7];
  const float* gw  = (const float*)d_in[8];
  const float* uw  = (const float*)d_in[9];
  const float* dw  = (const float*)d_in[10];
  const float* flw = (const float*)d_in[11];
  const float* sw  = (const float*)d_in[12];

  float* ws = (float*)d_ws;
  float* Vp   = ws;                     // 524288  (KSV*8*D)
  float* Op   = ws + 524288;            // 524288
  float* xr   = ws + 1048576;           // 8192
  float* h2   = ws + 1056768;           // 8192
  float* tw8  = ws + 1064960;           // 8
  int*   sel8 = (int*)(ws + 1064968);   // 8 (+pad to 128B line)
  float* Pgu  = ws + 1064992;           // KS5*4*8*F = 3670016 (128B-aligned)
  float* Dp   = ws + 4735008;           // KS6*2*8*D = 3670016 (128B-aligned)
  // no atomics, no barrier -> no zero-init; every read cell is written first.

  k_mvp_v<<<KSV, 256, 0, stream>>>(hs, ln1, vw, Vp);
  k_ored<<<KSV, 256, 0, stream>>>(Vp, ow, Op);
  k_mid<<<8, 256, 0, stream>>>(hs, Op, ln2, rw, xr, h2, tw8, sel8);
  k_gateup<<<dim3(14, KS5), 256, 0, stream>>>(h2, gw, uw, sel8, Pgu);
  k_down<<<2 * KS6, 256, 0, stream>>>(Pgu, dw, sel8, Dp);
  k_final<<<8, 256, 0, stream>>>(xr, Dp, tw8, sel8, flw, sw, (float*)d_out);
}